// Round 8
// baseline (58.760 us; speedup 1.0000x reference)
//
#include <hip/hip_runtime.h>
#include <math.h>

#define BB 4
#define LL 64
#define DD 64
#define NEG_ -1e9f

typedef _Float16 h2 __attribute__((ext_vector_type(2)));

__device__ __forceinline__ float rcp_(float x) { return __builtin_amdgcn_rcpf(x); }
__device__ __forceinline__ float fast_sigmoid(float x) { return rcp_(1.0f + __expf(-x)); }
// tanh(x) = 1 - 2/(exp(2x)+1); saturates correctly via exp->inf/0, rcp(inf)=0
__device__ __forceinline__ float fast_tanh(float x) { return fmaf(-2.0f, rcp_(__expf(2.0f * x) + 1.0f), 1.0f); }

// 4-wave attn: w-phase split over waves (k) and lanes (e-quad x d-offset) with
// float4 rel loads + shfl_xor d-reduce. Then scores/softmax (wave0), PV (all
// waves), out-proj + gx-proj (all 256 threads).
__global__ __launch_bounds__(256) void attn_kernel(
    const int* __restrict__ x, const int* __restrict__ r,
    const float* __restrict__ emb, const float* __restrict__ rel,
    const float* __restrict__ aW, const float* __restrict__ ab,
    const float* __restrict__ Wih, const float* __restrict__ bih,
    float* __restrict__ gx)
{
    const int i = blockIdx.x, b = blockIdx.y;
    const int tt = threadIdx.x, lane = tt & 63, wv = tt >> 6;
    __shared__ float o_lds[LL][DD + 1];
    __shared__ float w_lds[16][DD + 1];
    __shared__ float p_lds[LL];
    __shared__ float pv_part[4][DD];
    __shared__ float ao_lds[DD];
    __shared__ float o2_lds[DD];

    // stage o: thread covers row j=tt>>2, floats q*16..q*16+15 (coalesced float4)
    {
        const int j = tt >> 2, q = tt & 3;
        const int row = x[b * LL + j];
        const float4* src = (const float4*)(emb + row * DD + q * 16);
        const float4 v0 = src[0], v1 = src[1], v2 = src[2], v3 = src[3];
        float* dst = &o_lds[j][q * 16];
        dst[0] = v0.x; dst[1] = v0.y; dst[2] = v0.z; dst[3] = v0.w;
        dst[4] = v1.x; dst[5] = v1.y; dst[6] = v1.z; dst[7] = v1.w;
        dst[8] = v2.x; dst[9] = v2.y; dst[10] = v2.z; dst[11] = v2.w;
        dst[12] = v3.x; dst[13] = v3.y; dst[14] = v3.z; dst[15] = v3.w;
    }
    __syncthreads();

    // w-phase: wave wv handles k = wv*4+1 .. wv*4+4 (<=15).
    // lane = (dq=lane>>4, eq=lane&15): partial over d in {g*4+dq}, e-range eq*4..+3
    {
        const int eq = lane & 15, dq = lane >> 4;
#pragma unroll
        for (int kk = 0; kk < 4; kk++) {
            const int k = wv * 4 + kk + 1;
            if (k <= 15) {
                float4 acc = make_float4(0.f, 0.f, 0.f, 0.f);
                const float* relb = rel + k * 4096 + eq * 4;
#pragma unroll
                for (int g2 = 0; g2 < 16; g2++) {
                    const int d = g2 * 4 + dq;
                    const float od = o_lds[i][d];
                    const float4 rv4 = *(const float4*)(relb + d * 64);
                    acc.x = fmaf(od, rv4.x, acc.x);
                    acc.y = fmaf(od, rv4.y, acc.y);
                    acc.z = fmaf(od, rv4.z, acc.z);
                    acc.w = fmaf(od, rv4.w, acc.w);
                }
                acc.x += __shfl_xor(acc.x, 16, 64); acc.y += __shfl_xor(acc.y, 16, 64);
                acc.z += __shfl_xor(acc.z, 16, 64); acc.w += __shfl_xor(acc.w, 16, 64);
                acc.x += __shfl_xor(acc.x, 32, 64); acc.y += __shfl_xor(acc.y, 32, 64);
                acc.z += __shfl_xor(acc.z, 32, 64); acc.w += __shfl_xor(acc.w, 32, 64);
                if (dq == 0) {
                    float* wd = &w_lds[k][eq * 4];
                    wd[0] = acc.x; wd[1] = acc.y; wd[2] = acc.z; wd[3] = acc.w;
                }
            }
        }
    }
    __syncthreads();

    // scores + softmax over j: wave 0 (lane = j)
    if (wv == 0) {
        const int rv = r[(b * LL + i) * LL + lane];
        float s = NEG_;
        if (rv > 0) {
            float a0 = 0.f, a1 = 0.f;
#pragma unroll
            for (int e = 0; e < DD; e += 2) {
                a0 = fmaf(w_lds[rv][e + 0], o_lds[lane][e + 0], a0);
                a1 = fmaf(w_lds[rv][e + 1], o_lds[lane][e + 1], a1);
            }
            s = a0 + a1;
        }
        float mx = s;
        for (int off = 1; off < 64; off <<= 1) mx = fmaxf(mx, __shfl_xor(mx, off, 64));
        const float ex = __expf(s - mx);
        float sum = ex;
        for (int off = 1; off < 64; off <<= 1) sum += __shfl_xor(sum, off, 64);
        p_lds[lane] = ex * rcp_(sum);
    }
    __syncthreads();

    // PV: wave wv sums its 16 j's; lane = d
    {
        float acc = 0.f;
#pragma unroll
        for (int j = 0; j < 16; j++) {
            const int jj = wv * 16 + j;
            acc = fmaf(p_lds[jj], o_lds[jj][lane], acc);
        }
        pv_part[wv][lane] = acc;
    }
    __syncthreads();
    if (wv == 0)
        ao_lds[lane] = (pv_part[0][lane] + pv_part[1][lane]) + (pv_part[2][lane] + pv_part[3][lane]);
    __syncthreads();

    // o2: 4 threads per output row (row=tt>>2, q=tt&3 covers e=q*16..+15)
    {
        const int row = tt >> 2, q = tt & 3;
        float a = 0.f;
        const float4* wr4 = (const float4*)(aW + row * DD + q * 16);
#pragma unroll
        for (int e4 = 0; e4 < 4; e4++) {
            const float4 w4 = wr4[e4];
            const float* av = &ao_lds[q * 16 + e4 * 4];
            a = fmaf(av[0], w4.x, a); a = fmaf(av[1], w4.y, a);
            a = fmaf(av[2], w4.z, a); a = fmaf(av[3], w4.w, a);
        }
        a += __shfl_xor(a, 1, 64);
        a += __shfl_xor(a, 2, 64);
        if (q == 0) o2_lds[row] = a + ab[row];
    }
    __syncthreads();

    // gx: threads 0..191, g = tt: gx[g] = sum_e o2[e]*Wih[g,e] + bih[g]
    if (tt < 192) {
        float a = bih[tt];
        const float4* wg4 = (const float4*)(Wih + tt * DD);
#pragma unroll 4
        for (int e4 = 0; e4 < 16; e4++) {
            const float4 w4 = wg4[e4];
            const float* ov = &o2_lds[e4 * 4];
            a = fmaf(ov[0], w4.x, a); a = fmaf(ov[1], w4.y, a);
            a = fmaf(ov[2], w4.z, a); a = fmaf(ov[3], w4.w, a);
        }
        gx[(b * LL + i) * 192 + tt] = a;
    }
}

// ONE WAVE per batch, barrier-free scan. R8: h broadcast WITHOUT LDS —
// pair-pack h via shfl_xor+cvt_pkrtz, then 32x v_readlane (imm lane) -> SGPR,
// consumed directly by v_dot2_f32_f16. Zero lgkmcnt ops on the h chain;
// gx reads get explicit next-step prefetch; o3 write stays off-chain.
__global__ __launch_bounds__(64, 1) void gru_kernel(
    const float* __restrict__ gx, const float* __restrict__ Whh, const float* __restrict__ bhh,
    const float* __restrict__ oWih, const float* __restrict__ oWhh,
    const float* __restrict__ obih, const float* __restrict__ obhh,
    const int* __restrict__ lvec, float* __restrict__ cws)
{
    const int b = blockIdx.x, t = threadIdx.x;
    __shared__ float gx_lds[LL][192];      // 48 KB flat
    __shared__ float o3[LL][DD + 1];
    __shared__ float gx2[LL][4];
    __shared__ float p2[LL];

    // stage gx (this batch): 3072 float4 over 64 lanes = 48 each, coalesced
    {
        const float4* src = (const float4*)(gx + b * LL * 192);
        float4* dst = (float4*)&gx_lds[0][0];
#pragma unroll 4
        for (int f = 0; f < 48; f++) dst[f * 64 + t] = src[f * 64 + t];
    }

    // Whh rows t (r), 64+t (z), 128+t (n) as 32 packed-f16 pairs each;
    // whX[i] covers h elements (2i, 2i+1)
    h2 whr[32], whz[32], whn[32];
    {
        const float4* r0 = (const float4*)(Whh + t * DD);
        const float4* r1 = (const float4*)(Whh + (DD + t) * DD);
        const float4* r2 = (const float4*)(Whh + (2 * DD + t) * DD);
#pragma unroll
        for (int e = 0; e < 16; e++) {
            const float4 a = r0[e], bq = r1[e], c = r2[e];
            whr[2 * e + 0] = (h2){(_Float16)a.x, (_Float16)a.y};
            whr[2 * e + 1] = (h2){(_Float16)a.z, (_Float16)a.w};
            whz[2 * e + 0] = (h2){(_Float16)bq.x, (_Float16)bq.y};
            whz[2 * e + 1] = (h2){(_Float16)bq.z, (_Float16)bq.w};
            whn[2 * e + 0] = (h2){(_Float16)c.x, (_Float16)c.y};
            whn[2 * e + 1] = (h2){(_Float16)c.z, (_Float16)c.w};
        }
    }
#pragma unroll
    for (int i2 = 0; i2 < 32; i2++) {
        asm volatile("" : "+v"(whr[i2]), "+v"(whz[i2]), "+v"(whn[i2]));
    }
    const float br = bhh[t], bz = bhh[DD + t], bn = bhh[2 * DD + t];

    __syncthreads();   // gx_lds ready (single wave: just a drain)

    float h = 0.0f;
    int pki = 0;       // packed (h_even, h_odd) f16 pair, lanes 2k/2k+1 agree
    float g_r = gx_lds[0][t], g_z = gx_lds[0][DD + t], g_n = gx_lds[0][2 * DD + t];

#pragma unroll 1
    for (int l = 0; l < LL; l++) {
        // prefetch next step's gx (independent of h; completes under the dots)
        const int ln = (l + 1) & 63;
        const float pg_r = gx_lds[ln][t];
        const float pg_z = gx_lds[ln][DD + t];
        const float pg_n = gx_lds[ln][2 * DD + t];

        float ra0 = 0.f, ra1 = 0.f, ra2 = 0.f, ra3 = 0.f;
        float za0 = 0.f, za1 = 0.f, za2 = 0.f, za3 = 0.f;
        float na0 = 0.f, na1 = 0.f, na2 = 0.f, na3 = 0.f;
#pragma unroll
        for (int j = 0; j < 8; j++) {
            const h2 p0 = __builtin_bit_cast(h2, __builtin_amdgcn_readlane(pki, 8 * j + 0));
            const h2 p1 = __builtin_bit_cast(h2, __builtin_amdgcn_readlane(pki, 8 * j + 2));
            const h2 p2_ = __builtin_bit_cast(h2, __builtin_amdgcn_readlane(pki, 8 * j + 4));
            const h2 p3 = __builtin_bit_cast(h2, __builtin_amdgcn_readlane(pki, 8 * j + 6));
            ra0 = __builtin_amdgcn_fdot2(p0, whr[4 * j + 0], ra0, false);
            ra1 = __builtin_amdgcn_fdot2(p1, whr[4 * j + 1], ra1, false);
            ra2 = __builtin_amdgcn_fdot2(p2_, whr[4 * j + 2], ra2, false);
            ra3 = __builtin_amdgcn_fdot2(p3, whr[4 * j + 3], ra3, false);
            za0 = __builtin_amdgcn_fdot2(p0, whz[4 * j + 0], za0, false);
            za1 = __builtin_amdgcn_fdot2(p1, whz[4 * j + 1], za1, false);
            za2 = __builtin_amdgcn_fdot2(p2_, whz[4 * j + 2], za2, false);
            za3 = __builtin_amdgcn_fdot2(p3, whz[4 * j + 3], za3, false);
            na0 = __builtin_amdgcn_fdot2(p0, whn[4 * j + 0], na0, false);
            na1 = __builtin_amdgcn_fdot2(p1, whn[4 * j + 1], na1, false);
            na2 = __builtin_amdgcn_fdot2(p2_, whn[4 * j + 2], na2, false);
            na3 = __builtin_amdgcn_fdot2(p3, whn[4 * j + 3], na3, false);
        }
        const float hr = br + ((ra0 + ra1) + (ra2 + ra3));
        const float hz = bz + ((za0 + za1) + (za2 + za3));
        const float hn = bn + ((na0 + na1) + (na2 + na3));

        const float rg = fast_sigmoid(g_r + hr);
        const float zg = fast_sigmoid(g_z + hz);
        const float ng = fast_tanh(g_n + rg * hn);
        h = (1.0f - zg) * ng + zg * h;
        o3[l][t] = h;                       // off-chain (read after the loop)

        // pair-pack for next step's readlane broadcast (no LDS round-trip)
        const float hx = __shfl_xor(h, 1, 64);
        const float lo = (t & 1) ? hx : h;
        const float hi = (t & 1) ? h : hx;
        pki = __builtin_bit_cast(int, __builtin_amdgcn_cvt_pkrtz(lo, hi));

        g_r = pg_r; g_z = pg_z; g_n = pg_n;
    }
    __syncthreads();

    // output-GRU input projections: lane t handles row l=t (3 dots of 64)
    {
        float A0 = obih[0], A1 = obih[1], A2 = obih[2];
        const float* w0 = oWih;
        const float* w1 = oWih + DD;
        const float* w2 = oWih + 2 * DD;
#pragma unroll 8
        for (int e = 0; e < DD; e++) {
            const float ov = o3[t][e];
            A0 = fmaf(ov, w0[e], A0);
            A1 = fmaf(ov, w1[e], A1);
            A2 = fmaf(ov, w2[e], A2);
        }
        gx2[t][0] = A0; gx2[t][1] = A1; gx2[t][2] = A2;
    }
    __syncthreads();

    // H=1 scan (serial, lane 0) with next-step prefetch
    if (t == 0) {
        const float w0 = oWhh[0], w1 = oWhh[1], w2 = oWhh[2];
        const float c0 = obhh[0], c1 = obhh[1], c2 = obhh[2];
        float hh = 0.0f;
        float g0 = gx2[0][0], g1 = gx2[0][1], g2 = gx2[0][2];
#pragma unroll 1
        for (int l = 0; l < LL; l++) {
            const int ln = (l + 1) & 63;
            const float ng0 = gx2[ln][0], ng1 = gx2[ln][1], ng2 = gx2[ln][2];
            const float rg = fast_sigmoid(g0 + fmaf(hh, w0, c0));
            const float zg = fast_sigmoid(g1 + fmaf(hh, w1, c1));
            const float ng = fast_tanh(g2 + rg * fmaf(hh, w2, c2));
            hh = (1.0f - zg) * ng + zg * hh;
            p2[l] = hh;
            g0 = ng0; g1 = ng1; g2 = ng2;
        }
    }
    __syncthreads();

    // bug-faithful mask: col <= max_b(l[b]); wave softmax
    {
        const int maxl = max(max(lvec[0], lvec[1]), max(lvec[2], lvec[3]));
        const float v = (t <= maxl) ? p2[t] : NEG_;
        float mx = v;
        for (int off = 1; off < 64; off <<= 1) mx = fmaxf(mx, __shfl_xor(mx, off, 64));
        const float ex = __expf(v - mx);
        float sum = ex;
        for (int off = 1; off < 64; off <<= 1) sum += __shfl_xor(sum, off, 64);
        p2[t] = ex * rcp_(sum);
    }
    __syncthreads();

    {   // c[d=t] = sum_l p2[l]*o3[l][t]
        float acc = 0.f;
#pragma unroll 8
        for (int l = 0; l < LL; l++) acc = fmaf(p2[l], o3[l][t], acc);
        cws[b * DD + t] = acc;
    }
}

// Classifier + softmax + loss for all batches; writes all 9 outputs
__global__ void cls_kernel(const float* __restrict__ c_ws, const int* __restrict__ y,
                           const float* __restrict__ W1, const float* __restrict__ b1,
                           const float* __restrict__ W2, const float* __restrict__ b2,
                           float* __restrict__ out)
{
    const int t = threadIdx.x;
    __shared__ float c_lds[DD];
    __shared__ float h1[32];
    __shared__ float lg[2];
    float loss = 0.0f;
    for (int b = 0; b < BB; b++) {
        c_lds[t] = c_ws[b * DD + t];
        __syncthreads();
        if (t < 32) {
            float a = b1[t];
            const float* wr = W1 + t * DD;
            for (int d = 0; d < DD; d++) a = fmaf(c_lds[d], wr[d], a);
            h1[t] = fmaxf(a, 0.0f);
        }
        __syncthreads();
        if (t < 2) {
            float a = b2[t];
            const float* wr = W2 + t * 32;
            for (int m2 = 0; m2 < 32; m2++) a = fmaf(h1[m2], wr[m2], a);
            lg[t] = a;
        }
        __syncthreads();
        if (t == 0) {
            const float l0 = lg[0], l1 = lg[1];
            const float mx = fmaxf(l0, l1);
            const float e0 = __expf(l0 - mx), e1 = __expf(l1 - mx);
            const float s = e0 + e1;
            out[b * 2 + 0] = e0 / s;
            out[b * 2 + 1] = e1 / s;
            const float lp = ((y[b] == 1) ? l1 : l0) - mx - __logf(s);
            loss -= lp * 0.25f;
        }
        __syncthreads();
    }
    if (t == 0) out[8] = loss;
}

extern "C" void kernel_launch(void* const* d_in, const int* in_sizes, int n_in,
                              void* d_out, int out_size, void* d_ws, size_t ws_size,
                              hipStream_t stream)
{
    const int*   x    = (const int*)d_in[0];
    const int*   y    = (const int*)d_in[1];
    const int*   r    = (const int*)d_in[2];
    const int*   l    = (const int*)d_in[3];
    const float* emb  = (const float*)d_in[4];
    const float* rel  = (const float*)d_in[5];
    const float* aW   = (const float*)d_in[6];
    const float* ab   = (const float*)d_in[7];
    const float* Wih  = (const float*)d_in[8];
    const float* Whh  = (const float*)d_in[9];
    const float* bih  = (const float*)d_in[10];
    const float* bhh  = (const float*)d_in[11];
    const float* oWih = (const float*)d_in[12];
    const float* oWhh = (const float*)d_in[13];
    const float* obih = (const float*)d_in[14];
    const float* obhh = (const float*)d_in[15];
    const float* W1   = (const float*)d_in[16];
    const float* b1   = (const float*)d_in[17];
    const float* W2   = (const float*)d_in[18];
    const float* b2   = (const float*)d_in[19];

    float* ws  = (float*)d_ws;
    float* gx  = ws;                                   // B*L*192 = 49152 floats
    float* cws = ws + 49152;                           // B*D     =   256 floats

    attn_kernel<<<dim3(LL, BB), 256, 0, stream>>>(x, r, emb, rel, aW, ab, Wih, bih, gx);
    gru_kernel<<<BB, 64, 0, stream>>>(gx, Whh, bhh, oWih, oWhh, obih, obhh, l, cws);
    cls_kernel<<<1, DD, 0, stream>>>(cws, y, W1, b1, W2, b2, (float*)d_out);
}